// Round 1
// baseline (299.996 us; speedup 1.0000x reference)
//
#include <hip/hip_runtime.h>

#define N_NODES 50000
#define N_EDGES 800000
#define DIM 128
#define N_LAYERS 3

// fixed-capacity bucket: 64 ushort slots/node (128 B = exactly 2 lines).
// In-degree ~ Poisson(16); P(>64) ~ 1e-20. src ids < 50000 fit ushort.
#define CAP_LOG2 6
#define CAP (1 << CAP_LOG2)

typedef __attribute__((ext_vector_type(8))) short bf16x8;
typedef __attribute__((ext_vector_type(4))) float f32x4;

__device__ __forceinline__ unsigned short f2bf(float f) {
    unsigned int u = __float_as_uint(f);
    u += 0x7fffu + ((u >> 16) & 1u);   // RNE
    return (unsigned short)(u >> 16);
}
__device__ __forceinline__ float bfu2f_lo(unsigned int v) { return __uint_as_float(v << 16); }
__device__ __forceinline__ float bfu2f_hi(unsigned int v) { return __uint_as_float(v & 0xffff0000u); }

// ---------------- build (XCD-partitioned) + cvt ----------------
// Build floor = the 800k rank atomics (~43 µs, invariant under ILP x4/x8,
// overlay, nt on/off, ushort). Frozen.

#define NODE_RANGE ((N_NODES + 7) / 8)        // 6250 nodes per XCD range
#define EDGES_PER_BLOCK 2048                  // 256 thr x 8 edges
#define BUILD_CH ((N_EDGES + EDGES_PER_BLOCK - 1) / EDGES_PER_BLOCK)   // 391 chunks
#define BUILD_NB (BUILD_CH * 8)               // 3128 blocks
#define CVT_X_T (N_NODES * (DIM / 4))         // 1,600,000 float4s
#define CVT_W_T (6 * DIM * DIM)               // 98,304
#define CVT_NB  ((CVT_X_T + CVT_W_T + 255) / 256)   // 6634

__global__ void build_cvt_kernel(const int* __restrict__ src, const int* __restrict__ dst,
                                 int* __restrict__ counts, unsigned short* __restrict__ srcs_sorted,
                                 const float* __restrict__ x, unsigned short* __restrict__ z,
                                 const float* __restrict__ Ws1, const float* __restrict__ Ws2,
                                 unsigned short* __restrict__ wt) {
    if (blockIdx.x < BUILD_NB) {
        int r = blockIdx.x & 7;               // dst range; aligns with XCD round-robin dispatch
        int c = blockIdx.x >> 3;              // edge chunk
        int lo = r * NODE_RANGE;
        int hi = lo + NODE_RANGE;
        int base = c * EDGES_PER_BLOCK;
#pragma unroll
        for (int j = 0; j < 8; ++j) {
            int e = base + j * 256 + threadIdx.x;
            if (e < N_EDGES) {
                int d = dst[e];
                if (d >= lo && d < hi) {
                    int s = src[e];
                    int rk = atomicAdd(&counts[d], 1);
                    if (rk < CAP) srcs_sorted[(d << CAP_LOG2) + rk] = (unsigned short)s;
                }
            }
        }
    } else {
        int t = (blockIdx.x - BUILD_NB) * 256 + threadIdx.x;
        if (t < CVT_X_T) {
            float4 v = ((const float4*)x)[t];
            ushort4 o;
            o.x = f2bf(v.x); o.y = f2bf(v.y); o.z = f2bf(v.z); o.w = f2bf(v.w);
            ((ushort4*)z)[t] = o;
        } else if (t - CVT_X_T < CVT_W_T) {
            int u = t - CVT_X_T;
            int m = u >> 14;
            int r2 = u & 16383;
            int n = r2 >> 7;
            int k = r2 & 127;
            const float* Wm = (m < 3) ? (Ws1 + (size_t)m * DIM * DIM)
                                      : (Ws2 + (size_t)(m - 3) * DIM * DIM);
            wt[u] = f2bf(Wm[(size_t)k * DIM + n]);   // WT[m][n][k]
        }
    }
}

// ---------------- fused layer: h = agg(z); z' = relu(relu(h@W1+b1)@W2+b2) ----
// Tile = 16 nodes per 256-thread block; 50000 = 3125 * 16 exactly (no tail).
// Phase A: each of 4 waves aggregates 4 nodes (proven gather loop, 4 row
//          loads in flight per lane) -> 16x128 bf16 slab in LDS.
// Phase B: two MFMA stages straight out of LDS (wave tile 16x32, nt=2).
// bufh global round-trip (25.6 MB/layer) eliminated; MLP MFMA of other
// resident blocks overlaps this block's gather-wait.

#define TILE 16
#define T_STRIDE 132

template <bool LAST>
__global__ __launch_bounds__(256) void layer_fused(const unsigned short* __restrict__ z,
                                                   const int* __restrict__ counts,
                                                   const unsigned short* __restrict__ srcs,
                                                   const unsigned short* __restrict__ WT1,
                                                   const float* __restrict__ b1,
                                                   const unsigned short* __restrict__ WT2,
                                                   const float* __restrict__ b2,
                                                   void* __restrict__ Cout) {
    __shared__ unsigned short h_lds[TILE * T_STRIDE];
    __shared__ unsigned short t_lds[TILE * T_STRIDE];
    int wave = threadIdx.x >> 6;     // 0..3
    int lane = threadIdx.x & 63;
    int sub  = lane >> 4;
    int col  = lane & 15;
    int rowbase = blockIdx.x * TILE;
    const uint4* zp = (const uint4*)z;            // row stride = 16 uint4
    const unsigned int* sp = (const unsigned int*)srcs;   // 2 indices per uint

    // ---- Phase A: aggregation, 4 nodes per wave ----
#pragma unroll 1
    for (int nd = 0; nd < 4; ++nd) {
        int node = rowbase + wave * 4 + nd;       // always < N_NODES (exact tiling)

        float a0 = 0.f, a1 = 0.f, a2 = 0.f, a3 = 0.f, a4 = 0.f, a5 = 0.f, a6 = 0.f, a7 = 0.f;
        float b0 = 0.f, b1v = 0.f, b2v = 0.f, b3 = 0.f, b4 = 0.f, b5 = 0.f, b6 = 0.f, b7 = 0.f;

        int s = node << CAP_LOG2;                 // slot base (even)
        int deg = counts[node];
        if (deg > CAP) deg = CAP;
        int e = s + deg;
        int i = s;
        // 16-edge main loop: 2 pair loads, 4 uint4 row loads in flight per lane
        for (; i + 16 <= e; i += 16) {
            unsigned int p0 = sp[(i >> 1) + sub];         // edges i+2sub, i+2sub+1
            unsigned int p1 = sp[(i >> 1) + 4 + sub];     // edges i+8+2sub, i+8+2sub+1
            int eA0 = (int)(p0 & 0xffffu), eB0 = (int)(p0 >> 16);
            int eA1 = (int)(p1 & 0xffffu), eB1 = (int)(p1 >> 16);
            uint4 vA0 = zp[(size_t)eA0 * 16 + col];
            uint4 vB0 = zp[(size_t)eB0 * 16 + col];
            uint4 vA1 = zp[(size_t)eA1 * 16 + col];
            uint4 vB1 = zp[(size_t)eB1 * 16 + col];
            a0 += bfu2f_lo(vA0.x); a1 += bfu2f_hi(vA0.x); a2 += bfu2f_lo(vA0.y); a3 += bfu2f_hi(vA0.y);
            a4 += bfu2f_lo(vA0.z); a5 += bfu2f_hi(vA0.z); a6 += bfu2f_lo(vA0.w); a7 += bfu2f_hi(vA0.w);
            b0 += bfu2f_lo(vB0.x); b1v += bfu2f_hi(vB0.x); b2v += bfu2f_lo(vB0.y); b3 += bfu2f_hi(vB0.y);
            b4 += bfu2f_lo(vB0.z); b5 += bfu2f_hi(vB0.z); b6 += bfu2f_lo(vB0.w); b7 += bfu2f_hi(vB0.w);
            a0 += bfu2f_lo(vA1.x); a1 += bfu2f_hi(vA1.x); a2 += bfu2f_lo(vA1.y); a3 += bfu2f_hi(vA1.y);
            a4 += bfu2f_lo(vA1.z); a5 += bfu2f_hi(vA1.z); a6 += bfu2f_lo(vA1.w); a7 += bfu2f_hi(vA1.w);
            b0 += bfu2f_lo(vB1.x); b1v += bfu2f_hi(vB1.x); b2v += bfu2f_lo(vB1.y); b3 += bfu2f_hi(vB1.y);
            b4 += bfu2f_lo(vB1.z); b5 += bfu2f_hi(vB1.z); b6 += bfu2f_lo(vB1.w); b7 += bfu2f_hi(vB1.w);
        }
        for (; i + 8 <= e; i += 8) {
            unsigned int pair = sp[(i >> 1) + sub];
            int eA = (int)(pair & 0xffffu);
            int eB = (int)(pair >> 16);
            uint4 vA = zp[(size_t)eA * 16 + col];
            uint4 vB = zp[(size_t)eB * 16 + col];
            a0 += bfu2f_lo(vA.x); a1 += bfu2f_hi(vA.x); a2 += bfu2f_lo(vA.y); a3 += bfu2f_hi(vA.y);
            a4 += bfu2f_lo(vA.z); a5 += bfu2f_hi(vA.z); a6 += bfu2f_lo(vA.w); a7 += bfu2f_hi(vA.w);
            b0 += bfu2f_lo(vB.x); b1v += bfu2f_hi(vB.x); b2v += bfu2f_lo(vB.y); b3 += bfu2f_hi(vB.y);
            b4 += bfu2f_lo(vB.z); b5 += bfu2f_hi(vB.z); b6 += bfu2f_lo(vB.w); b7 += bfu2f_hi(vB.w);
        }
        // tail (0..7 edges): sub handles slots i+2*sub and i+2*sub+1 if in range
        {
            int j0 = i + sub * 2;
            if (j0 < e) {
                int eA = (int)srcs[j0];
                uint4 vA = zp[(size_t)eA * 16 + col];
                a0 += bfu2f_lo(vA.x); a1 += bfu2f_hi(vA.x); a2 += bfu2f_lo(vA.y); a3 += bfu2f_hi(vA.y);
                a4 += bfu2f_lo(vA.z); a5 += bfu2f_hi(vA.z); a6 += bfu2f_lo(vA.w); a7 += bfu2f_hi(vA.w);
            }
            if (j0 + 1 < e) {
                int eB = (int)srcs[j0 + 1];
                uint4 vB = zp[(size_t)eB * 16 + col];
                b0 += bfu2f_lo(vB.x); b1v += bfu2f_hi(vB.x); b2v += bfu2f_lo(vB.y); b3 += bfu2f_hi(vB.y);
                b4 += bfu2f_lo(vB.z); b5 += bfu2f_hi(vB.z); b6 += bfu2f_lo(vB.w); b7 += bfu2f_hi(vB.w);
            }
        }

        a0 += b0; a1 += b1v; a2 += b2v; a3 += b3; a4 += b4; a5 += b5; a6 += b6; a7 += b7;
        a0 += __shfl_xor(a0, 16); a1 += __shfl_xor(a1, 16); a2 += __shfl_xor(a2, 16); a3 += __shfl_xor(a3, 16);
        a4 += __shfl_xor(a4, 16); a5 += __shfl_xor(a5, 16); a6 += __shfl_xor(a6, 16); a7 += __shfl_xor(a7, 16);
        a0 += __shfl_xor(a0, 32); a1 += __shfl_xor(a1, 32); a2 += __shfl_xor(a2, 32); a3 += __shfl_xor(a3, 32);
        a4 += __shfl_xor(a4, 32); a5 += __shfl_xor(a5, 32); a6 += __shfl_xor(a6, 32); a7 += __shfl_xor(a7, 32);

        // self term (eps = 0)
        uint4 sv = zp[(size_t)node * 16 + col];
        a0 += bfu2f_lo(sv.x); a1 += bfu2f_hi(sv.x); a2 += bfu2f_lo(sv.y); a3 += bfu2f_hi(sv.y);
        a4 += bfu2f_lo(sv.z); a5 += bfu2f_hi(sv.z); a6 += bfu2f_lo(sv.w); a7 += bfu2f_hi(sv.w);

        if (sub == 0) {
            int lrow = wave * 4 + nd;
            unsigned int w0 = (unsigned int)f2bf(a0) | ((unsigned int)f2bf(a1) << 16);
            unsigned int w1 = (unsigned int)f2bf(a2) | ((unsigned int)f2bf(a3) << 16);
            unsigned int w2 = (unsigned int)f2bf(a4) | ((unsigned int)f2bf(a5) << 16);
            unsigned int w3 = (unsigned int)f2bf(a6) | ((unsigned int)f2bf(a7) << 16);
            unsigned short* hp = &h_lds[lrow * T_STRIDE + col * 8];
            // stride 132 ushorts = 264 B: col*16 B offsets are 8 B aligned -> uint2 stores
            ((unsigned int*)hp)[0] = w0;
            ((unsigned int*)hp)[1] = w1;
            ((unsigned int*)(hp + 4))[0] = w2;
            ((unsigned int*)(hp + 4))[1] = w3;
        }
    }
    __syncthreads();

    // ---- Phase B: MLP, wave tile 16 rows x 32 cols ----
    int quad = sub;
    int r16  = col;
    int wn = wave * 32;

    f32x4 acc[2];
#pragma unroll
    for (int nt = 0; nt < 2; ++nt)
#pragma unroll
        for (int ii = 0; ii < 4; ++ii) acc[nt][ii] = 0.f;

#pragma unroll
    for (int ks = 0; ks < 4; ++ks) {
        int k = ks * 32 + quad * 8;
        bf16x8 a = *(const bf16x8*)&h_lds[r16 * T_STRIDE + k];
#pragma unroll
        for (int nt = 0; nt < 2; ++nt) {
            int c = wn + nt * 16 + r16;
            bf16x8 b = *(const bf16x8*)(WT1 + (size_t)c * DIM + k);
            acc[nt] = __builtin_amdgcn_mfma_f32_16x16x32_bf16(a, b, acc[nt], 0, 0, 0);
        }
    }

#pragma unroll
    for (int nt = 0; nt < 2; ++nt) {
        int c = wn + nt * 16 + r16;
        float bv = b1[c];
#pragma unroll
        for (int ii = 0; ii < 4; ++ii) {
            float v = fmaxf(acc[nt][ii] + bv, 0.f);
            t_lds[(quad * 4 + ii) * T_STRIDE + c] = f2bf(v);
        }
    }
    __syncthreads();

    f32x4 acc2[2];
#pragma unroll
    for (int nt = 0; nt < 2; ++nt)
#pragma unroll
        for (int ii = 0; ii < 4; ++ii) acc2[nt][ii] = 0.f;

#pragma unroll
    for (int ks = 0; ks < 4; ++ks) {
        int k = ks * 32 + quad * 8;
        bf16x8 a = *(const bf16x8*)&t_lds[r16 * T_STRIDE + k];
#pragma unroll
        for (int nt = 0; nt < 2; ++nt) {
            int c = wn + nt * 16 + r16;
            bf16x8 b = *(const bf16x8*)(WT2 + (size_t)c * DIM + k);
            acc2[nt] = __builtin_amdgcn_mfma_f32_16x16x32_bf16(a, b, acc2[nt], 0, 0, 0);
        }
    }

#pragma unroll
    for (int nt = 0; nt < 2; ++nt) {
        int c = wn + nt * 16 + r16;
        float bv = b2[c];
#pragma unroll
        for (int ii = 0; ii < 4; ++ii) {
            int row = rowbase + quad * 4 + ii;     // always < N_NODES (exact tiling)
            float v = fmaxf(acc2[nt][ii] + bv, 0.f);
            if (LAST) __builtin_nontemporal_store(v, &((float*)Cout)[(size_t)row * DIM + c]);
            else ((unsigned short*)Cout)[(size_t)row * DIM + c] = f2bf(v);
        }
    }
}

// ---------------- launch ----------------

extern "C" void kernel_launch(void* const* d_in, const int* in_sizes, int n_in,
                              void* d_out, int out_size, void* d_ws, size_t ws_size,
                              hipStream_t stream) {
    const float* x   = (const float*)d_in[0];
    const float* Ws1 = (const float*)d_in[1];
    const float* bs1 = (const float*)d_in[2];
    const float* Ws2 = (const float*)d_in[3];
    const float* bs2 = (const float*)d_in[4];
    const int*   ei  = (const int*)d_in[5];   // int32 (JAX x64 disabled)
    const int* src = ei;
    const int* dst = ei + N_EDGES;
    float* out = (float*)d_out;

    char* ws = (char*)d_ws;
    size_t off = 0;
    auto carve = [&](size_t bytes) {
        void* p = ws + off;
        off += (bytes + 255) & ~(size_t)255;
        return p;
    };
    unsigned short* zA   = (unsigned short*)carve((size_t)N_NODES * DIM * 2);
    unsigned short* zB   = (unsigned short*)carve((size_t)N_NODES * DIM * 2);
    unsigned short* wt   = (unsigned short*)carve((size_t)6 * DIM * DIM * 2);
    int* counts = (int*)carve((size_t)N_NODES * 4);
    unsigned short* srcs = (unsigned short*)carve((size_t)N_NODES * CAP * 2);   // 6.4 MB buckets

    // build (XCD-partitioned hist+scatter) + cvt
    hipMemsetAsync(counts, 0, (size_t)N_NODES * 4, stream);
    build_cvt_kernel<<<BUILD_NB + CVT_NB, 256, 0, stream>>>(src, dst, counts, srcs,
                                                            x, zA, Ws1, Ws2, wt);

    const int grid = N_NODES / TILE;   // 3125, exact

    unsigned short* zin = zA;
    unsigned short* znext = zB;
    for (int l = 0; l < N_LAYERS; ++l) {
        if (l == N_LAYERS - 1) {
            layer_fused<true><<<grid, 256, 0, stream>>>(
                zin, counts, srcs, wt + (size_t)l * DIM * DIM, bs1 + (size_t)l * DIM,
                wt + (size_t)(3 + l) * DIM * DIM, bs2 + (size_t)l * DIM, out);
        } else {
            layer_fused<false><<<grid, 256, 0, stream>>>(
                zin, counts, srcs, wt + (size_t)l * DIM * DIM, bs1 + (size_t)l * DIM,
                wt + (size_t)(3 + l) * DIM * DIM, bs2 + (size_t)l * DIM, znext);
            unsigned short* tmp = zin; zin = znext; znext = tmp;
        }
    }
}

// Round 2
// 276.316 us; speedup vs baseline: 1.0857x; 1.0857x over previous
//
#include <hip/hip_runtime.h>

#define N_NODES 50000
#define N_EDGES 800000
#define DIM 128
#define N_LAYERS 3

// fixed-capacity bucket: 64 ushort slots/node (128 B = exactly 2 lines).
// In-degree ~ Poisson(16); P(>64) ~ 1e-20. src ids < 50000 fit ushort.
#define CAP_LOG2 6
#define CAP (1 << CAP_LOG2)

typedef __attribute__((ext_vector_type(8))) short bf16x8;
typedef __attribute__((ext_vector_type(4))) float f32x4;

__device__ __forceinline__ unsigned short f2bf(float f) {
    unsigned int u = __float_as_uint(f);
    u += 0x7fffu + ((u >> 16) & 1u);   // RNE
    return (unsigned short)(u >> 16);
}
__device__ __forceinline__ float bfu2f_lo(unsigned int v) { return __uint_as_float(v << 16); }
__device__ __forceinline__ float bfu2f_hi(unsigned int v) { return __uint_as_float(v & 0xffff0000u); }

// ---------------- build (XCD-partitioned) + cvt ----------------
// Build floor = the 800k rank atomics (~43 µs, invariant under ILP x4/x8,
// overlay, nt on/off, ushort). Frozen.

#define NODE_RANGE ((N_NODES + 7) / 8)        // 6250 nodes per XCD range
#define EDGES_PER_BLOCK 2048                  // 256 thr x 8 edges
#define BUILD_CH ((N_EDGES + EDGES_PER_BLOCK - 1) / EDGES_PER_BLOCK)   // 391 chunks
#define BUILD_NB (BUILD_CH * 8)               // 3128 blocks
#define CVT_X_T (N_NODES * (DIM / 4))         // 1,600,000 float4s
#define CVT_W_T (6 * DIM * DIM)               // 98,304
#define CVT_NB  ((CVT_X_T + CVT_W_T + 255) / 256)   // 6634

__global__ void build_cvt_kernel(const int* __restrict__ src, const int* __restrict__ dst,
                                 int* __restrict__ counts, unsigned short* __restrict__ srcs_sorted,
                                 const float* __restrict__ x, unsigned short* __restrict__ z,
                                 const float* __restrict__ Ws1, const float* __restrict__ Ws2,
                                 unsigned short* __restrict__ wt) {
    if (blockIdx.x < BUILD_NB) {
        int r = blockIdx.x & 7;               // dst range; aligns with XCD round-robin dispatch
        int c = blockIdx.x >> 3;              // edge chunk
        int lo = r * NODE_RANGE;
        int hi = lo + NODE_RANGE;
        int base = c * EDGES_PER_BLOCK;
#pragma unroll
        for (int j = 0; j < 8; ++j) {
            int e = base + j * 256 + threadIdx.x;
            if (e < N_EDGES) {
                int d = dst[e];
                if (d >= lo && d < hi) {
                    int s = src[e];
                    int rk = atomicAdd(&counts[d], 1);
                    if (rk < CAP) srcs_sorted[(d << CAP_LOG2) + rk] = (unsigned short)s;
                }
            }
        }
    } else {
        int t = (blockIdx.x - BUILD_NB) * 256 + threadIdx.x;
        if (t < CVT_X_T) {
            float4 v = ((const float4*)x)[t];
            ushort4 o;
            o.x = f2bf(v.x); o.y = f2bf(v.y); o.z = f2bf(v.z); o.w = f2bf(v.w);
            ((ushort4*)z)[t] = o;
        } else if (t - CVT_X_T < CVT_W_T) {
            int u = t - CVT_X_T;
            int m = u >> 14;
            int r2 = u & 16383;
            int n = r2 >> 7;
            int k = r2 & 127;
            const float* Wm = (m < 3) ? (Ws1 + (size_t)m * DIM * DIM)
                                      : (Ws2 + (size_t)(m - 3) * DIM * DIM);
            wt[u] = f2bf(Wm[(size_t)k * DIM + n]);   // WT[m][n][k]
        }
    }
}

// ---------------- gather: one full wave aggregates one node ----------------
// Verbatim proven loop: sub = lane>>4, col = lane&15; 16-edge main loop keeps
// 4 uint4 row loads in flight per lane; zero intra-wave divergence (e is
// wave-uniform). Writes the node's bf16 row into LDS (hrow) from sub==0.

__device__ __forceinline__ void gather_node(int node, const uint4* __restrict__ zp,
                                            const unsigned int* __restrict__ sp,
                                            const int* __restrict__ counts,
                                            const unsigned short* __restrict__ srcs,
                                            int sub, int col, unsigned short* hrow) {
    float a0 = 0.f, a1 = 0.f, a2 = 0.f, a3 = 0.f, a4 = 0.f, a5 = 0.f, a6 = 0.f, a7 = 0.f;
    float b0 = 0.f, b1 = 0.f, b2 = 0.f, b3 = 0.f, b4 = 0.f, b5 = 0.f, b6 = 0.f, b7 = 0.f;

    int s = node << CAP_LOG2;                     // slot base (even)
    int deg = counts[node];
    if (deg > CAP) deg = CAP;
    int e = s + deg;
    int i = s;
    // 16-edge main loop: 2 pair loads, 4 uint4 row loads in flight per lane
    for (; i + 16 <= e; i += 16) {
        unsigned int p0 = sp[(i >> 1) + sub];         // edges i+2sub, i+2sub+1
        unsigned int p1 = sp[(i >> 1) + 4 + sub];     // edges i+8+2sub, i+8+2sub+1
        int eA0 = (int)(p0 & 0xffffu), eB0 = (int)(p0 >> 16);
        int eA1 = (int)(p1 & 0xffffu), eB1 = (int)(p1 >> 16);
        uint4 vA0 = zp[(size_t)eA0 * 16 + col];
        uint4 vB0 = zp[(size_t)eB0 * 16 + col];
        uint4 vA1 = zp[(size_t)eA1 * 16 + col];
        uint4 vB1 = zp[(size_t)eB1 * 16 + col];
        a0 += bfu2f_lo(vA0.x); a1 += bfu2f_hi(vA0.x); a2 += bfu2f_lo(vA0.y); a3 += bfu2f_hi(vA0.y);
        a4 += bfu2f_lo(vA0.z); a5 += bfu2f_hi(vA0.z); a6 += bfu2f_lo(vA0.w); a7 += bfu2f_hi(vA0.w);
        b0 += bfu2f_lo(vB0.x); b1 += bfu2f_hi(vB0.x); b2 += bfu2f_lo(vB0.y); b3 += bfu2f_hi(vB0.y);
        b4 += bfu2f_lo(vB0.z); b5 += bfu2f_hi(vB0.z); b6 += bfu2f_lo(vB0.w); b7 += bfu2f_hi(vB0.w);
        a0 += bfu2f_lo(vA1.x); a1 += bfu2f_hi(vA1.x); a2 += bfu2f_lo(vA1.y); a3 += bfu2f_hi(vA1.y);
        a4 += bfu2f_lo(vA1.z); a5 += bfu2f_hi(vA1.z); a6 += bfu2f_lo(vA1.w); a7 += bfu2f_hi(vA1.w);
        b0 += bfu2f_lo(vB1.x); b1 += bfu2f_hi(vB1.x); b2 += bfu2f_lo(vB1.y); b3 += bfu2f_hi(vB1.y);
        b4 += bfu2f_lo(vB1.z); b5 += bfu2f_hi(vB1.z); b6 += bfu2f_lo(vB1.w); b7 += bfu2f_hi(vB1.w);
    }
    for (; i + 8 <= e; i += 8) {
        unsigned int pair = sp[(i >> 1) + sub];
        int eA = (int)(pair & 0xffffu);
        int eB = (int)(pair >> 16);
        uint4 vA = zp[(size_t)eA * 16 + col];
        uint4 vB = zp[(size_t)eB * 16 + col];
        a0 += bfu2f_lo(vA.x); a1 += bfu2f_hi(vA.x); a2 += bfu2f_lo(vA.y); a3 += bfu2f_hi(vA.y);
        a4 += bfu2f_lo(vA.z); a5 += bfu2f_hi(vA.z); a6 += bfu2f_lo(vA.w); a7 += bfu2f_hi(vA.w);
        b0 += bfu2f_lo(vB.x); b1 += bfu2f_hi(vB.x); b2 += bfu2f_lo(vB.y); b3 += bfu2f_hi(vB.y);
        b4 += bfu2f_lo(vB.z); b5 += bfu2f_hi(vB.z); b6 += bfu2f_lo(vB.w); b7 += bfu2f_hi(vB.w);
    }
    // tail (0..7 edges): sub handles slots i+2*sub and i+2*sub+1 if in range
    {
        int j0 = i + sub * 2;
        if (j0 < e) {
            int eA = (int)srcs[j0];
            uint4 vA = zp[(size_t)eA * 16 + col];
            a0 += bfu2f_lo(vA.x); a1 += bfu2f_hi(vA.x); a2 += bfu2f_lo(vA.y); a3 += bfu2f_hi(vA.y);
            a4 += bfu2f_lo(vA.z); a5 += bfu2f_hi(vA.z); a6 += bfu2f_lo(vA.w); a7 += bfu2f_hi(vA.w);
        }
        if (j0 + 1 < e) {
            int eB = (int)srcs[j0 + 1];
            uint4 vB = zp[(size_t)eB * 16 + col];
            b0 += bfu2f_lo(vB.x); b1 += bfu2f_hi(vB.x); b2 += bfu2f_lo(vB.y); b3 += bfu2f_hi(vB.y);
            b4 += bfu2f_lo(vB.z); b5 += bfu2f_hi(vB.z); b6 += bfu2f_lo(vB.w); b7 += bfu2f_hi(vB.w);
        }
    }

    a0 += b0; a1 += b1; a2 += b2; a3 += b3; a4 += b4; a5 += b5; a6 += b6; a7 += b7;
    a0 += __shfl_xor(a0, 16); a1 += __shfl_xor(a1, 16); a2 += __shfl_xor(a2, 16); a3 += __shfl_xor(a3, 16);
    a4 += __shfl_xor(a4, 16); a5 += __shfl_xor(a5, 16); a6 += __shfl_xor(a6, 16); a7 += __shfl_xor(a7, 16);
    a0 += __shfl_xor(a0, 32); a1 += __shfl_xor(a1, 32); a2 += __shfl_xor(a2, 32); a3 += __shfl_xor(a3, 32);
    a4 += __shfl_xor(a4, 32); a5 += __shfl_xor(a5, 32); a6 += __shfl_xor(a6, 32); a7 += __shfl_xor(a7, 32);

    // self term (eps = 0)
    uint4 sv = zp[(size_t)node * 16 + col];
    a0 += bfu2f_lo(sv.x); a1 += bfu2f_hi(sv.x); a2 += bfu2f_lo(sv.y); a3 += bfu2f_hi(sv.y);
    a4 += bfu2f_lo(sv.z); a5 += bfu2f_hi(sv.z); a6 += bfu2f_lo(sv.w); a7 += bfu2f_hi(sv.w);

    if (sub == 0) {
        unsigned short* hp = hrow + col * 8;      // 8 B aligned (stride 264 B)
        ((unsigned int*)hp)[0] = (unsigned int)f2bf(a0) | ((unsigned int)f2bf(a1) << 16);
        ((unsigned int*)hp)[1] = (unsigned int)f2bf(a2) | ((unsigned int)f2bf(a3) << 16);
        ((unsigned int*)(hp + 4))[0] = (unsigned int)f2bf(a4) | ((unsigned int)f2bf(a5) << 16);
        ((unsigned int*)(hp + 4))[1] = (unsigned int)f2bf(a6) | ((unsigned int)f2bf(a7) << 16);
    }
}

// ---------------- pipelined fused layer ----------------
// 512 threads (8 waves), grid = 1024 = exactly 4 blocks/CU (32 waves/CU).
// Block pipelines its ~3 tiles: while MLP'ing tile t-1 it gathers tile t.
// Phase A: MLP stage1(t-1) + gather node[wave] of t   -> hbuf[pg]
// Phase B: MLP stage2(t-1) + gather node[8+wave] of t -> hbuf[pg]
// Every phase issues both MFMA and gather misses from every wave -> the
// L2-miss pipe (the measured ~1.3-1.7 TB/s bottleneck) never drains while
// MLP runs. Fill iter is pure gather (no waste); drain iter is one cheap MLP.

#define TILE 16
#define T_STRIDE 132
#define NT_TILES (N_NODES / TILE)   // 3125, exact
#define GRID_L 1024                 // 4 blocks/CU, all co-resident

template <bool LAST>
__global__ __launch_bounds__(512, 8) void layer_pipe(const unsigned short* __restrict__ z,
                                                     const int* __restrict__ counts,
                                                     const unsigned short* __restrict__ srcs,
                                                     const unsigned short* __restrict__ WT1,
                                                     const float* __restrict__ b1,
                                                     const unsigned short* __restrict__ WT2,
                                                     const float* __restrict__ b2,
                                                     void* __restrict__ Cout) {
    __shared__ unsigned short hbuf[2][TILE * T_STRIDE];   // double-buffered agg rows
    __shared__ unsigned short t_lds[TILE * T_STRIDE];     // MLP intermediate

    const uint4* zp = (const uint4*)z;                    // row stride = 16 uint4
    const unsigned int* sp = (const unsigned int*)srcs;   // 2 indices per uint

    int wave = threadIdx.x >> 6;     // 0..7
    int lane = threadIdx.x & 63;
    int sub  = lane >> 4;            // gather sub-slot / MLP quad
    int col  = lane & 15;            // gather col / MLP r16
    int c    = wave * 16 + col;      // MLP output column (8 waves x 16 = 128)

    int t = blockIdx.x;              // tile being gathered
    int tm = -1;                     // tile being MLP'd
    int pg = 0;                      // hbuf parity gather writes to

    while (t < NT_TILES || tm >= 0) {
        bool hasG = (t < NT_TILES);
        unsigned short* hw = hbuf[pg];
        const unsigned short* hr = hbuf[pg ^ 1];

        // ---- Phase A: MLP stage1(tm) + gather node[wave] of t ----
        if (tm >= 0) {
            f32x4 acc;
#pragma unroll
            for (int ii = 0; ii < 4; ++ii) acc[ii] = 0.f;
#pragma unroll
            for (int ks = 0; ks < 4; ++ks) {
                int k = ks * 32 + sub * 8;
                bf16x8 a = *(const bf16x8*)&hr[col * T_STRIDE + k];
                bf16x8 b = *(const bf16x8*)(WT1 + (size_t)c * DIM + k);
                acc = __builtin_amdgcn_mfma_f32_16x16x32_bf16(a, b, acc, 0, 0, 0);
            }
            float bv = b1[c];
#pragma unroll
            for (int ii = 0; ii < 4; ++ii)
                t_lds[(sub * 4 + ii) * T_STRIDE + c] = f2bf(fmaxf(acc[ii] + bv, 0.f));
        }
        if (hasG)
            gather_node(t * TILE + wave, zp, sp, counts, srcs, sub, col,
                        &hw[wave * T_STRIDE]);
        __syncthreads();

        // ---- Phase B: MLP stage2(tm) + gather node[8+wave] of t ----
        if (tm >= 0) {
            f32x4 acc2;
#pragma unroll
            for (int ii = 0; ii < 4; ++ii) acc2[ii] = 0.f;
#pragma unroll
            for (int ks = 0; ks < 4; ++ks) {
                int k = ks * 32 + sub * 8;
                bf16x8 a = *(const bf16x8*)&t_lds[col * T_STRIDE + k];
                bf16x8 b = *(const bf16x8*)(WT2 + (size_t)c * DIM + k);
                acc2 = __builtin_amdgcn_mfma_f32_16x16x32_bf16(a, b, acc2, 0, 0, 0);
            }
            float bv = b2[c];
#pragma unroll
            for (int ii = 0; ii < 4; ++ii) {
                int row = tm * TILE + sub * 4 + ii;   // always < N_NODES (exact tiling)
                float v = fmaxf(acc2[ii] + bv, 0.f);
                if (LAST) __builtin_nontemporal_store(v, &((float*)Cout)[(size_t)row * DIM + c]);
                else ((unsigned short*)Cout)[(size_t)row * DIM + c] = f2bf(v);
            }
        }
        if (hasG)
            gather_node(t * TILE + 8 + wave, zp, sp, counts, srcs, sub, col,
                        &hw[(8 + wave) * T_STRIDE]);
        __syncthreads();

        tm = hasG ? t : -1;
        pg ^= 1;
        t += GRID_L;
    }
}

// ---------------- launch ----------------

extern "C" void kernel_launch(void* const* d_in, const int* in_sizes, int n_in,
                              void* d_out, int out_size, void* d_ws, size_t ws_size,
                              hipStream_t stream) {
    const float* x   = (const float*)d_in[0];
    const float* Ws1 = (const float*)d_in[1];
    const float* bs1 = (const float*)d_in[2];
    const float* Ws2 = (const float*)d_in[3];
    const float* bs2 = (const float*)d_in[4];
    const int*   ei  = (const int*)d_in[5];   // int32 (JAX x64 disabled)
    const int* src = ei;
    const int* dst = ei + N_EDGES;
    float* out = (float*)d_out;

    char* ws = (char*)d_ws;
    size_t off = 0;
    auto carve = [&](size_t bytes) {
        void* p = ws + off;
        off += (bytes + 255) & ~(size_t)255;
        return p;
    };
    unsigned short* zA   = (unsigned short*)carve((size_t)N_NODES * DIM * 2);
    unsigned short* zB   = (unsigned short*)carve((size_t)N_NODES * DIM * 2);
    unsigned short* wt   = (unsigned short*)carve((size_t)6 * DIM * DIM * 2);
    int* counts = (int*)carve((size_t)N_NODES * 4);
    unsigned short* srcs = (unsigned short*)carve((size_t)N_NODES * CAP * 2);   // 6.4 MB buckets

    // build (XCD-partitioned hist+scatter) + cvt
    hipMemsetAsync(counts, 0, (size_t)N_NODES * 4, stream);
    build_cvt_kernel<<<BUILD_NB + CVT_NB, 256, 0, stream>>>(src, dst, counts, srcs,
                                                            x, zA, Ws1, Ws2, wt);

    unsigned short* zin = zA;
    unsigned short* znext = zB;
    for (int l = 0; l < N_LAYERS; ++l) {
        if (l == N_LAYERS - 1) {
            layer_pipe<true><<<GRID_L, 512, 0, stream>>>(
                zin, counts, srcs, wt + (size_t)l * DIM * DIM, bs1 + (size_t)l * DIM,
                wt + (size_t)(3 + l) * DIM * DIM, bs2 + (size_t)l * DIM, out);
        } else {
            layer_pipe<false><<<GRID_L, 512, 0, stream>>>(
                zin, counts, srcs, wt + (size_t)l * DIM * DIM, bs1 + (size_t)l * DIM,
                wt + (size_t)(3 + l) * DIM * DIM, bs2 + (size_t)l * DIM, znext);
            unsigned short* tmp = zin; zin = znext; znext = tmp;
        }
    }
}